// Round 1
// baseline (293.539 us; speedup 1.0000x reference)
//
#include <hip/hip_runtime.h>

#define HH 512
#define WW 512
#define HWSZ (512 * 512)
#define NCH 32
#define NLF 64
#define WSTRIDE 288          // floats per leaf in fused weight table
#define WS_WALL_OFF 128      // ws[0..53]=norm split wts, ws[64..127]=b_all, ws[128..]=w_all
#define THRESH 0.4054651081081644f  // ln(1.5): sigmoid(v)<0.6  <=>  v<ln(1.5)

// ---------------- prep: build fused weight table in workspace ----------------
// ws layout (floats):
//   [0, 54)                : normalized split weights, [f][ky*3+kx]
//   [64, 128)              : b_all[l] = b_pred[l] + mean(b_pred)
//   [128, 128 + 64*288)    : w_all[l][t*32 + c] = w_pred[l][c][t] + wsum[c][t]/64
__global__ void prep_kernel(const float* __restrict__ w_split,
                            const float* __restrict__ w_pred,
                            const float* __restrict__ b_pred,
                            float* __restrict__ ws) {
  const int tid = threadIdx.x;
  const int blk = blockIdx.x;
  if (blk < 64) {
    // fused weights for leaf l = blk ; tid enumerates (c,t), flat = c*9+t = tid
    if (tid < 288) {
      const int c = tid / 9, t = tid % 9;
      float s = 0.f;
      #pragma unroll 8
      for (int l = 0; l < 64; ++l) s += w_pred[l * 288 + tid];
      s *= (1.0f / 64.0f);
      ws[WS_WALL_OFF + blk * WSTRIDE + t * 32 + c] = w_pred[blk * 288 + tid] + s;
    }
  } else {
    // normalized split weights
    if (tid < 6) {
      float w[9];
      float s = 0.f;
      #pragma unroll
      for (int e = 0; e < 9; ++e) {
        float v = fmaxf(w_split[tid * 9 + e], 0.f);
        w[e] = v;
        s += v;
      }
      const float add = (s < 0.1f) ? (0.1f / 9.0f) : 0.0f;
      #pragma unroll
      for (int e = 0; e < 9; ++e) ws[tid * 9 + e] = w[e] + add;
    }
    // biases
    if (tid >= 64 && tid < 128) {
      float s = 0.f;
      for (int j = 0; j < 64; ++j) s += b_pred[j];
      ws[64 + (tid - 64)] = b_pred[tid - 64] + s * (1.0f / 64.0f);
    }
  }
}

// load 6-float window [xx0-1 .. xx0+4] of one row; edges clamped+masked to 0
__device__ __forceinline__ void load6(const float* __restrict__ rowp, int xx0,
                                      int offL, int offR, float lm, float rm,
                                      float w[6]) {
  const float4 c4 = *(const float4*)(rowp + xx0);
  w[0] = rowp[offL] * lm;
  w[1] = c4.x;
  w[2] = c4.y;
  w[3] = c4.z;
  w[4] = c4.w;
  w[5] = rowp[offR] * rm;
}

// accumulate the fused 32ch x 3x3 conv for 4 consecutive pixels.
// SAME=true: all 4 pixels share lf[0]'s filter (single weight stream).
template <bool SAME>
__device__ __forceinline__ void conv_accum(const float* __restrict__ dbase,
                                           const float* __restrict__ wall,
                                           const int* __restrict__ lf, int yy,
                                           int xx0, int offL, int offR,
                                           float lm, float rm, float4 acc[4]) {
  const float* wl0 = wall + lf[0] * WSTRIDE;
  const float* wl1 = wall + lf[1] * WSTRIDE;
  const float* wl2 = wall + lf[2] * WSTRIDE;
  const float* wl3 = wall + lf[3] * WSTRIDE;
  #pragma unroll 2
  for (int cg = 0; cg < 8; ++cg) {
    const float* ch0 = dbase + cg * 4 * HWSZ;
    #pragma unroll
    for (int dy = 0; dy < 3; ++dy) {
      const int ry = yy + dy - 1;
      if ((unsigned)ry < 512u) {
        const float* r0 = ch0 + ry * 512;
        const float* r1 = r0 + HWSZ;
        const float* r2 = r1 + HWSZ;
        const float* r3 = r2 + HWSZ;
        float a[6], b[6], c[6], d[6];
        load6(r0, xx0, offL, offR, lm, rm, a);
        load6(r1, xx0, offL, offR, lm, rm, b);
        load6(r2, xx0, offL, offR, lm, rm, c);
        load6(r3, xx0, offL, offR, lm, rm, d);
        #pragma unroll
        for (int dx = 0; dx < 3; ++dx) {
          const int woff = (dy * 3 + dx) * 32 + cg * 4;
          const float4 w0 = *(const float4*)(wl0 + woff);
          const float4 w1 = SAME ? w0 : *(const float4*)(wl1 + woff);
          const float4 w2 = SAME ? w0 : *(const float4*)(wl2 + woff);
          const float4 w3 = SAME ? w0 : *(const float4*)(wl3 + woff);
          acc[0].x = fmaf(a[0 + dx], w0.x, acc[0].x);
          acc[0].y = fmaf(b[0 + dx], w0.y, acc[0].y);
          acc[0].z = fmaf(c[0 + dx], w0.z, acc[0].z);
          acc[0].w = fmaf(d[0 + dx], w0.w, acc[0].w);
          acc[1].x = fmaf(a[1 + dx], w1.x, acc[1].x);
          acc[1].y = fmaf(b[1 + dx], w1.y, acc[1].y);
          acc[1].z = fmaf(c[1 + dx], w1.z, acc[1].z);
          acc[1].w = fmaf(d[1 + dx], w1.w, acc[1].w);
          acc[2].x = fmaf(a[2 + dx], w2.x, acc[2].x);
          acc[2].y = fmaf(b[2 + dx], w2.y, acc[2].y);
          acc[2].z = fmaf(c[2 + dx], w2.z, acc[2].z);
          acc[2].w = fmaf(d[2 + dx], w2.w, acc[2].w);
          acc[3].x = fmaf(a[3 + dx], w3.x, acc[3].x);
          acc[3].y = fmaf(b[3 + dx], w3.y, acc[3].y);
          acc[3].z = fmaf(c[3 + dx], w3.z, acc[3].z);
          acc[3].w = fmaf(d[3 + dx], w3.w, acc[3].w);
        }
      }
    }
  }
}

// tile: 128 wide x 8 high per block of 256 threads.
// lane handles 4 consecutive x; wave = 2 rows of 32 lanes.
__global__ __launch_bounds__(256, 4) void main_kernel(
    const float* __restrict__ x, const float* __restrict__ data,
    const float* __restrict__ ws, float* __restrict__ out) {
  const int tid = threadIdx.x;
  const int bx = blockIdx.x;   // 0..3
  const int by = blockIdx.y;   // 0..63
  const int n = blockIdx.z;    // 0..3
  const int xx0 = bx * 128 + (tid & 31) * 4;
  const int yy = by * 8 + (tid >> 5);

  const int offL = max(xx0 - 1, 0);
  const int offR = min(xx0 + 4, 511);
  const float lm = (xx0 > 0) ? 1.f : 0.f;
  const float rm = (xx0 < 508) ? 1.f : 0.f;

  // ---------- split-tree leaf for the 4 pixels ----------
  const float* xim = x + (size_t)n * HWSZ;
  float xw[3][6];
  #pragma unroll
  for (int dy = 0; dy < 3; ++dy) {
    const int ry = yy + dy - 1;
    if ((unsigned)ry < 512u) {
      load6(xim + ry * 512, xx0, offL, offR, lm, rm, xw[dy]);
    } else {
      #pragma unroll
      for (int j = 0; j < 6; ++j) xw[dy][j] = 0.f;
    }
  }
  int lf[4] = {0, 0, 0, 0};
  #pragma unroll
  for (int f = 0; f < 6; ++f) {
    float v0 = 0.f, v1 = 0.f, v2 = 0.f, v3 = 0.f;
    #pragma unroll
    for (int dy = 0; dy < 3; ++dy) {
      #pragma unroll
      for (int dx = 0; dx < 3; ++dx) {
        const float wv = ws[f * 9 + dy * 3 + dx];
        v0 = fmaf(xw[dy][0 + dx], wv, v0);
        v1 = fmaf(xw[dy][1 + dx], wv, v1);
        v2 = fmaf(xw[dy][2 + dx], wv, v2);
        v3 = fmaf(xw[dy][3 + dx], wv, v3);
      }
    }
    const int bit = 32 >> f;  // filter 0 is the MSB (2^(D-1))
    if (v0 < THRESH) lf[0] |= bit;
    if (v1 < THRESH) lf[1] |= bit;
    if (v2 < THRESH) lf[2] |= bit;
    if (v3 < THRESH) lf[3] |= bit;
  }

  // ---------- fused (base + selected) conv ----------
  float4 acc[4];
  #pragma unroll
  for (int p = 0; p < 4; ++p) acc[p] = make_float4(0.f, 0.f, 0.f, 0.f);

  const float* dbase = data + (size_t)n * NCH * HWSZ;
  const bool same = (lf[0] == lf[1]) && (lf[1] == lf[2]) && (lf[2] == lf[3]);
  if (__all((int)same)) {
    conv_accum<true>(dbase, ws + WS_WALL_OFF, lf, yy, xx0, offL, offR, lm, rm, acc);
  } else {
    conv_accum<false>(dbase, ws + WS_WALL_OFF, lf, yy, xx0, offL, offR, lm, rm, acc);
  }

  float4 res;
  res.x = acc[0].x + acc[0].y + acc[0].z + acc[0].w + ws[64 + lf[0]];
  res.y = acc[1].x + acc[1].y + acc[1].z + acc[1].w + ws[64 + lf[1]];
  res.z = acc[2].x + acc[2].y + acc[2].z + acc[2].w + ws[64 + lf[2]];
  res.w = acc[3].x + acc[3].y + acc[3].z + acc[3].w + ws[64 + lf[3]];
  *(float4*)(out + (size_t)n * HWSZ + yy * 512 + xx0) = res;
}

extern "C" void kernel_launch(void* const* d_in, const int* in_sizes, int n_in,
                              void* d_out, int out_size, void* d_ws,
                              size_t ws_size, hipStream_t stream) {
  const float* x = (const float*)d_in[0];        // [4,1,512,512]
  const float* data = (const float*)d_in[1];     // [4,32,512,512]
  const float* w_split = (const float*)d_in[2];  // [6,1,3,3]
  const float* w_pred = (const float*)d_in[3];   // [64,32,3,3]
  const float* b_pred = (const float*)d_in[4];   // [64]
  float* out = (float*)d_out;                    // [4,512,512]
  float* ws = (float*)d_ws;                      // needs 128+64*288 floats (~74 KB)

  prep_kernel<<<65, 320, 0, stream>>>(w_split, w_pred, b_pred, ws);
  main_kernel<<<dim3(4, 64, 4), 256, 0, stream>>>(x, data, ws, out);
}

// Round 4
// 276.594 us; speedup vs baseline: 1.0613x; 1.0613x over previous
//
#include <hip/hip_runtime.h>

#define HWSZ (512 * 512)
#define NCH 32
#define WSTRIDE 288          // floats per leaf in fused weight table
#define WS_WALL_OFF 128      // ws[0..53]=norm split wts, ws[64..127]=b_all, ws[128..]=w_all
#define THRESH 0.4054651081081644f  // ln(1.5): sigmoid(v)<0.6  <=>  v<ln(1.5)

// ---------------- prep: build fused weight table in workspace ----------------
// ws layout (floats):
//   [0, 54)                : normalized split weights, [f][ky*3+kx]
//   [64, 128)              : b_all[l] = b_pred[l] + mean(b_pred)
//   [128, 128 + 64*288)    : w_all[l][t*32 + c] = w_pred[l][c][t] + wsum[c][t]/64
__global__ void prep_kernel(const float* __restrict__ w_split,
                            const float* __restrict__ w_pred,
                            const float* __restrict__ b_pred,
                            float* __restrict__ ws) {
  const int tid = threadIdx.x;
  const int blk = blockIdx.x;
  if (blk < 64) {
    if (tid < 288) {
      const int c = tid / 9, t = tid % 9;
      float s = 0.f;
      #pragma unroll 8
      for (int l = 0; l < 64; ++l) s += w_pred[l * 288 + tid];
      s *= (1.0f / 64.0f);
      ws[WS_WALL_OFF + blk * WSTRIDE + t * 32 + c] = w_pred[blk * 288 + tid] + s;
    }
  } else {
    if (tid < 6) {
      float w[9];
      float s = 0.f;
      #pragma unroll
      for (int e = 0; e < 9; ++e) {
        float v = fmaxf(w_split[tid * 9 + e], 0.f);
        w[e] = v;
        s += v;
      }
      const float add = (s < 0.1f) ? (0.1f / 9.0f) : 0.0f;
      #pragma unroll
      for (int e = 0; e < 9; ++e) ws[tid * 9 + e] = w[e] + add;
    }
    if (tid >= 64 && tid < 128) {
      float s = 0.f;
      #pragma unroll 8
      for (int j = 0; j < 64; ++j) s += b_pred[j];
      ws[64 + (tid - 64)] = b_pred[tid - 64] + s * (1.0f / 64.0f);
    }
  }
}

// ---------------- main ----------------
// Block: 256 threads = 4 waves. Wave = one output row of 128 px (64 lanes x 2 px).
// Block tile: 128 wide x 4 rows. Grid (4, 128, 4) = 2048 blocks -> 8 blocks/CU
// -> 32 waves/CU -> 8 waves/SIMD (VGPR must stay <= 64; body kept lean, cg rolled).
__global__ __launch_bounds__(256, 8) void main_kernel(
    const float* __restrict__ x, const float* __restrict__ data,
    const float* __restrict__ ws, float* __restrict__ out) {
  const int tid = threadIdx.x;
  const int lane = tid & 63;
  const int wvid = tid >> 6;   // 0..3
  const int bx = blockIdx.x;   // 0..3
  const int by = blockIdx.y;   // 0..127
  const int n = blockIdx.z;    // 0..3
  const int xx0 = bx * 128 + lane * 2;
  const int yy = by * 4 + wvid;

  const bool isL = (lane == 0);
  const bool isR = (lane == 63);
  const bool isEdge = isL || isR;
  const int ecol = isL ? (xx0 - 1) : (xx0 + 2);       // only used by edge lanes
  const int ecolc = min(max(ecol, 0), 511);
  const float emask = (ecol >= 0 && ecol < 512) ? 1.f : 0.f;

  // ---------- split-tree leaves for the 2 pixels ----------
  const float* xim = x + (size_t)n * HWSZ;
  float xwin[3][4];  // [dy][{left, p0, p1, right}]
  #pragma unroll
  for (int dy = 0; dy < 3; ++dy) {
    const int ry = yy + dy - 1;
    if ((unsigned)ry < 512u) {
      const float* rp = xim + ry * 512;
      const float2 c2 = *(const float2*)(rp + xx0);
      float ev = 0.f;
      if (isEdge) ev = rp[ecolc] * emask;
      float lft = __shfl(c2.y, tid - 1);
      float rgt = __shfl(c2.x, tid + 1);
      if (isL) lft = ev;
      if (isR) rgt = ev;
      xwin[dy][0] = lft; xwin[dy][1] = c2.x; xwin[dy][2] = c2.y; xwin[dy][3] = rgt;
    } else {
      xwin[dy][0] = xwin[dy][1] = xwin[dy][2] = xwin[dy][3] = 0.f;
    }
  }
  int lf0 = 0, lf1 = 0;
  #pragma unroll
  for (int f = 0; f < 6; ++f) {
    float v0 = 0.f, v1 = 0.f;
    #pragma unroll
    for (int dy = 0; dy < 3; ++dy) {
      #pragma unroll
      for (int dx = 0; dx < 3; ++dx) {
        const float wv = ws[f * 9 + dy * 3 + dx];
        v0 = fmaf(xwin[dy][dx], wv, v0);
        v1 = fmaf(xwin[dy][dx + 1], wv, v1);
      }
    }
    const int bit = 32 >> f;  // filter 0 is the MSB
    if (v0 < THRESH) lf0 |= bit;
    if (v1 < THRESH) lf1 |= bit;
  }

  // ---------- fused (base + selected) conv ----------
  const float* wall = ws + WS_WALL_OFF;
  const float* wl0 = wall + lf0 * WSTRIDE;
  const float* wl1 = wall + lf1 * WSTRIDE;
  const float* dbase = data + (size_t)n * NCH * HWSZ;

  float4 acc0 = make_float4(0.f, 0.f, 0.f, 0.f);
  float4 acc1 = make_float4(0.f, 0.f, 0.f, 0.f);

  #pragma unroll 1
  for (int cg = 0; cg < 8; ++cg) {
    const float* ch0 = dbase + (size_t)cg * 4 * HWSZ;
    #pragma unroll
    for (int dy = 0; dy < 3; ++dy) {
      const int ry = yy + dy - 1;
      if ((unsigned)ry < 512u) {
        const float* r0 = ch0 + ry * 512;
        const float2 a2 = *(const float2*)(r0 + xx0);
        const float2 b2 = *(const float2*)(r0 + HWSZ + xx0);
        const float2 c2 = *(const float2*)(r0 + 2 * HWSZ + xx0);
        const float2 d2 = *(const float2*)(r0 + 3 * HWSZ + xx0);
        float ea = 0.f, eb = 0.f, ec = 0.f, ed = 0.f;
        if (isEdge) {
          ea = r0[ecolc] * emask;
          eb = r0[HWSZ + ecolc] * emask;
          ec = r0[2 * HWSZ + ecolc] * emask;
          ed = r0[3 * HWSZ + ecolc] * emask;
        }
        float la = __shfl(a2.y, tid - 1), ra = __shfl(a2.x, tid + 1);
        float lb = __shfl(b2.y, tid - 1), rb = __shfl(b2.x, tid + 1);
        float lc = __shfl(c2.y, tid - 1), rc = __shfl(c2.x, tid + 1);
        float ld = __shfl(d2.y, tid - 1), rd = __shfl(d2.x, tid + 1);
        if (isL) { la = ea; lb = eb; lc = ec; ld = ed; }
        if (isR) { ra = ea; rb = eb; rc = ec; rd = ed; }

        const int tbase = dy * 3 * 32 + cg * 4;
        // dx = 0: px0 uses left, px1 uses p0
        {
          const float4 w0 = *(const float4*)(wl0 + tbase);
          const float4 w1 = *(const float4*)(wl1 + tbase);
          acc0.x = fmaf(la, w0.x, acc0.x); acc1.x = fmaf(a2.x, w1.x, acc1.x);
          acc0.y = fmaf(lb, w0.y, acc0.y); acc1.y = fmaf(b2.x, w1.y, acc1.y);
          acc0.z = fmaf(lc, w0.z, acc0.z); acc1.z = fmaf(c2.x, w1.z, acc1.z);
          acc0.w = fmaf(ld, w0.w, acc0.w); acc1.w = fmaf(d2.x, w1.w, acc1.w);
        }
        // dx = 1: px0 uses p0, px1 uses p1
        {
          const float4 w0 = *(const float4*)(wl0 + tbase + 32);
          const float4 w1 = *(const float4*)(wl1 + tbase + 32);
          acc0.x = fmaf(a2.x, w0.x, acc0.x); acc1.x = fmaf(a2.y, w1.x, acc1.x);
          acc0.y = fmaf(b2.x, w0.y, acc0.y); acc1.y = fmaf(b2.y, w1.y, acc1.y);
          acc0.z = fmaf(c2.x, w0.z, acc0.z); acc1.z = fmaf(c2.y, w1.z, acc1.z);
          acc0.w = fmaf(d2.x, w0.w, acc0.w); acc1.w = fmaf(d2.y, w1.w, acc1.w);
        }
        // dx = 2: px0 uses p1, px1 uses right
        {
          const float4 w0 = *(const float4*)(wl0 + tbase + 64);
          const float4 w1 = *(const float4*)(wl1 + tbase + 64);
          acc0.x = fmaf(a2.y, w0.x, acc0.x); acc1.x = fmaf(ra, w1.x, acc1.x);
          acc0.y = fmaf(b2.y, w0.y, acc0.y); acc1.y = fmaf(rb, w1.y, acc1.y);
          acc0.z = fmaf(c2.y, w0.z, acc0.z); acc1.z = fmaf(rc, w1.z, acc1.z);
          acc0.w = fmaf(d2.y, w0.w, acc0.w); acc1.w = fmaf(rd, w1.w, acc1.w);
        }
      }
    }
  }

  const float res0 = acc0.x + acc0.y + acc0.z + acc0.w + ws[64 + lf0];
  const float res1 = acc1.x + acc1.y + acc1.z + acc1.w + ws[64 + lf1];
  *(float2*)(out + (size_t)n * HWSZ + yy * 512 + xx0) = make_float2(res0, res1);
}

extern "C" void kernel_launch(void* const* d_in, const int* in_sizes, int n_in,
                              void* d_out, int out_size, void* d_ws,
                              size_t ws_size, hipStream_t stream) {
  const float* x = (const float*)d_in[0];        // [4,1,512,512]
  const float* data = (const float*)d_in[1];     // [4,32,512,512]
  const float* w_split = (const float*)d_in[2];  // [6,1,3,3]
  const float* w_pred = (const float*)d_in[3];   // [64,32,3,3]
  const float* b_pred = (const float*)d_in[4];   // [64]
  float* out = (float*)d_out;                    // [4,512,512]
  float* ws = (float*)d_ws;                      // 128 + 64*288 floats (~74 KB)

  prep_kernel<<<65, 320, 0, stream>>>(w_split, w_pred, b_pred, ws);
  main_kernel<<<dim3(4, 128, 4), 256, 0, stream>>>(x, data, ws, out);
}

// Round 6
// 244.203 us; speedup vs baseline: 1.2020x; 1.1326x over previous
//
#include <hip/hip_runtime.h>

#define HWSZ (512 * 512)
#define NCH 32
#define WSTRIDE 292          // padded stride (292 % 32 == 4 -> leaves spread over 8 bank groups)
#define NW (64 * WSTRIDE)    // 18688 floats = 74752 B
#define WS_WALL_OFF 128      // ws[0..53]=norm split wts, ws[64..127]=b_all, ws[128..]=w_all
#define THRESH 0.4054651081081644f  // ln(1.5): sigmoid(v)<0.6  <=>  v<ln(1.5)

// ---------------- prep: build fused weight table in workspace ----------------
// ws layout (floats):
//   [0, 54)              : normalized split weights, [f][ky*3+kx]
//   [64, 128)            : b_all[l] = b_pred[l] + mean(b_pred)
//   [128, 128 + 64*292)  : w_all[l][t*32 + c] = w_pred[l][c][t] + wsum[c][t]/64  (stride-padded)
__global__ void prep_kernel(const float* __restrict__ w_split,
                            const float* __restrict__ w_pred,
                            const float* __restrict__ b_pred,
                            float* __restrict__ ws) {
  const int tid = threadIdx.x;
  const int blk = blockIdx.x;
  if (blk < 64) {
    if (tid < 288) {
      const int c = tid / 9, t = tid % 9;
      float s = 0.f;
      #pragma unroll 8
      for (int l = 0; l < 64; ++l) s += w_pred[l * 288 + tid];
      s *= (1.0f / 64.0f);
      ws[WS_WALL_OFF + blk * WSTRIDE + t * 32 + c] = w_pred[blk * 288 + tid] + s;
    }
    // zero the 4-float pad so the LDS bulk copy reads defined memory
    if (tid >= 288 && tid < 292) {
      ws[WS_WALL_OFF + blk * WSTRIDE + tid] = 0.f;
    }
  } else {
    if (tid < 6) {
      float w[9];
      float s = 0.f;
      #pragma unroll
      for (int e = 0; e < 9; ++e) {
        float v = fmaxf(w_split[tid * 9 + e], 0.f);
        w[e] = v;
        s += v;
      }
      const float add = (s < 0.1f) ? (0.1f / 9.0f) : 0.0f;
      #pragma unroll
      for (int e = 0; e < 9; ++e) ws[tid * 9 + e] = w[e] + add;
    }
    if (tid >= 64 && tid < 128) {
      float s = 0.f;
      #pragma unroll 8
      for (int j = 0; j < 64; ++j) s += b_pred[j];
      ws[64 + (tid - 64)] = b_pred[tid - 64] + s * (1.0f / 64.0f);
    }
  }
}

// ---------------- main ----------------
// Block: 1024 threads = 16 waves; wave = one row of 128 px (64 lanes x 2 px).
// Block tile: 128 wide x 16 rows. Grid (4, 32, 4) = 512 blocks = 2 blocks/CU.
// LDS: full fused weight table (75 KB) -> 2 blocks/CU = 150 KB <= 160 KB,
// 32 waves/CU = 8 waves/SIMD (VGPR <= 64 enforced by launch_bounds).
__global__ __launch_bounds__(1024, 8) void main_kernel(
    const float* __restrict__ x, const float* __restrict__ data,
    const float* __restrict__ ws, float* __restrict__ out) {
  __shared__ float s_w[NW + 64];

  const int tid = threadIdx.x;

  // ---- issue LDS fill first; it overlaps the split-leaf computation ----
  {
    const float4* __restrict__ src = (const float4*)(ws + WS_WALL_OFF);
    float4* dst = (float4*)s_w;
    #pragma unroll 1
    for (int i = tid; i < NW / 4; i += 1024) dst[i] = src[i];
    if (tid < 64) s_w[NW + tid] = ws[64 + tid];
  }

  const int lane = tid & 63;
  const int wvid = tid >> 6;   // 0..15
  const int bx = blockIdx.x;   // 0..3
  const int by = blockIdx.y;   // 0..31
  const int n = blockIdx.z;    // 0..3
  const int xx0 = bx * 128 + lane * 2;
  const int yy = by * 16 + wvid;

  const bool isL = (lane == 0);
  const bool isR = (lane == 63);
  const bool isEdge = isL || isR;
  const int ecol = isL ? (xx0 - 1) : (xx0 + 2);       // only used by edge lanes
  const int ecolc = min(max(ecol, 0), 511);
  const float emask = (ecol >= 0 && ecol < 512) ? 1.f : 0.f;

  // ---------- split-tree leaves for the 2 pixels (global mem only) ----------
  const float* xim = x + (size_t)n * HWSZ;
  float xwin[3][4];  // [dy][{left, p0, p1, right}]
  #pragma unroll
  for (int dy = 0; dy < 3; ++dy) {
    const int ry = yy + dy - 1;
    if ((unsigned)ry < 512u) {
      const float* rp = xim + ry * 512;
      const float2 c2 = *(const float2*)(rp + xx0);
      float ev = 0.f;
      if (isEdge) ev = rp[ecolc] * emask;
      float lft = __shfl(c2.y, tid - 1);
      float rgt = __shfl(c2.x, tid + 1);
      if (isL) lft = ev;
      if (isR) rgt = ev;
      xwin[dy][0] = lft; xwin[dy][1] = c2.x; xwin[dy][2] = c2.y; xwin[dy][3] = rgt;
    } else {
      xwin[dy][0] = xwin[dy][1] = xwin[dy][2] = xwin[dy][3] = 0.f;
    }
  }
  int lf0 = 0, lf1 = 0;
  #pragma unroll
  for (int f = 0; f < 6; ++f) {
    float v0 = 0.f, v1 = 0.f;
    #pragma unroll
    for (int dy = 0; dy < 3; ++dy) {
      #pragma unroll
      for (int dx = 0; dx < 3; ++dx) {
        const float wv = ws[f * 9 + dy * 3 + dx];
        v0 = fmaf(xwin[dy][dx], wv, v0);
        v1 = fmaf(xwin[dy][dx + 1], wv, v1);
      }
    }
    const int bit = 32 >> f;  // filter 0 is the MSB
    if (v0 < THRESH) lf0 |= bit;
    if (v1 < THRESH) lf1 |= bit;
  }

  __syncthreads();  // weight table ready

  // ---------- fused (base + selected) conv; weights from LDS ----------
  const float* wl0 = s_w + lf0 * WSTRIDE;
  const float* wl1 = s_w + lf1 * WSTRIDE;
  const float* dbase = data + (size_t)n * NCH * HWSZ;

  float4 acc0 = make_float4(0.f, 0.f, 0.f, 0.f);
  float4 acc1 = make_float4(0.f, 0.f, 0.f, 0.f);

  #pragma unroll 1
  for (int cg = 0; cg < 8; ++cg) {
    const float* ch0 = dbase + (size_t)cg * 4 * HWSZ;
    #pragma unroll
    for (int dy = 0; dy < 3; ++dy) {
      const int ry = yy + dy - 1;
      if ((unsigned)ry < 512u) {
        const float* r0 = ch0 + ry * 512;
        const float2 a2 = *(const float2*)(r0 + xx0);
        const float2 b2 = *(const float2*)(r0 + HWSZ + xx0);
        const float2 c2 = *(const float2*)(r0 + 2 * HWSZ + xx0);
        const float2 d2 = *(const float2*)(r0 + 3 * HWSZ + xx0);
        float ea = 0.f, eb = 0.f, ec = 0.f, ed = 0.f;
        if (isEdge) {
          ea = r0[ecolc] * emask;
          eb = r0[HWSZ + ecolc] * emask;
          ec = r0[2 * HWSZ + ecolc] * emask;
          ed = r0[3 * HWSZ + ecolc] * emask;
        }
        float la = __shfl(a2.y, tid - 1), ra = __shfl(a2.x, tid + 1);
        float lb = __shfl(b2.y, tid - 1), rb = __shfl(b2.x, tid + 1);
        float lc = __shfl(c2.y, tid - 1), rc = __shfl(c2.x, tid + 1);
        float ld = __shfl(d2.y, tid - 1), rd = __shfl(d2.x, tid + 1);
        if (isL) { la = ea; lb = eb; lc = ec; ld = ed; }
        if (isR) { ra = ea; rb = eb; rc = ec; rd = ed; }

        const int tbase = dy * 3 * 32 + cg * 4;
        // dx = 0: px0 uses left, px1 uses p0
        {
          const float4 w0 = *(const float4*)(wl0 + tbase);
          const float4 w1 = *(const float4*)(wl1 + tbase);
          acc0.x = fmaf(la, w0.x, acc0.x); acc1.x = fmaf(a2.x, w1.x, acc1.x);
          acc0.y = fmaf(lb, w0.y, acc0.y); acc1.y = fmaf(b2.x, w1.y, acc1.y);
          acc0.z = fmaf(lc, w0.z, acc0.z); acc1.z = fmaf(c2.x, w1.z, acc1.z);
          acc0.w = fmaf(ld, w0.w, acc0.w); acc1.w = fmaf(d2.x, w1.w, acc1.w);
        }
        // dx = 1: px0 uses p0, px1 uses p1
        {
          const float4 w0 = *(const float4*)(wl0 + tbase + 32);
          const float4 w1 = *(const float4*)(wl1 + tbase + 32);
          acc0.x = fmaf(a2.x, w0.x, acc0.x); acc1.x = fmaf(a2.y, w1.x, acc1.x);
          acc0.y = fmaf(b2.x, w0.y, acc0.y); acc1.y = fmaf(b2.y, w1.y, acc1.y);
          acc0.z = fmaf(c2.x, w0.z, acc0.z); acc1.z = fmaf(c2.y, w1.z, acc1.z);
          acc0.w = fmaf(d2.x, w0.w, acc0.w); acc1.w = fmaf(d2.y, w1.w, acc1.w);
        }
        // dx = 2: px0 uses p1, px1 uses right
        {
          const float4 w0 = *(const float4*)(wl0 + tbase + 64);
          const float4 w1 = *(const float4*)(wl1 + tbase + 64);
          acc0.x = fmaf(a2.y, w0.x, acc0.x); acc1.x = fmaf(ra, w1.x, acc1.x);
          acc0.y = fmaf(b2.y, w0.y, acc0.y); acc1.y = fmaf(rb, w1.y, acc1.y);
          acc0.z = fmaf(c2.y, w0.z, acc0.z); acc1.z = fmaf(rc, w1.z, acc1.z);
          acc0.w = fmaf(d2.y, w0.w, acc0.w); acc1.w = fmaf(rd, w1.w, acc1.w);
        }
      }
    }
  }

  const float res0 = acc0.x + acc0.y + acc0.z + acc0.w + s_w[NW + lf0];
  const float res1 = acc1.x + acc1.y + acc1.z + acc1.w + s_w[NW + lf1];
  *(float2*)(out + (size_t)n * HWSZ + yy * 512 + xx0) = make_float2(res0, res1);
}

extern "C" void kernel_launch(void* const* d_in, const int* in_sizes, int n_in,
                              void* d_out, int out_size, void* d_ws,
                              size_t ws_size, hipStream_t stream) {
  const float* x = (const float*)d_in[0];        // [4,1,512,512]
  const float* data = (const float*)d_in[1];     // [4,32,512,512]
  const float* w_split = (const float*)d_in[2];  // [6,1,3,3]
  const float* w_pred = (const float*)d_in[3];   // [64,32,3,3]
  const float* b_pred = (const float*)d_in[4];   // [64]
  float* out = (float*)d_out;                    // [4,512,512]
  float* ws = (float*)d_ws;                      // 128 + 64*292 floats (~74 KB)

  prep_kernel<<<65, 320, 0, stream>>>(w_split, w_pred, b_pred, ws);
  main_kernel<<<dim3(4, 32, 4), 1024, 0, stream>>>(x, data, ws, out);
}